// Round 2
// baseline (410.274 us; speedup 1.0000x reference)
//
#include <hip/hip_runtime.h>

// ---------------------------------------------------------------------------
// SelfAttention fused pipeline for MI355X (gfx950)
// N=4, S=2048, E=1024, H=16, D=64.
// Pipeline: [prep Wo^T bf16] -> [per-head QKV proj fp32->bf16] ->
//           [flash attention bf16 MFMA] -> [out GEMM bf16 MFMA + bias, fp32]
// Workspace layout (needs ~69 MB):
//   qbf/kbf/vbf : (N,H,S,D) bf16, 16 MB each
//   obf         : (N,S,E)   bf16, 16 MB
//   wot         : Wo^T (E,E) bf16, 2 MB
// ---------------------------------------------------------------------------

typedef unsigned short u16;
typedef __attribute__((ext_vector_type(8))) short s16x8;
typedef __attribute__((ext_vector_type(8))) unsigned short u16x8;
typedef __attribute__((ext_vector_type(4))) float f32x4;
typedef __attribute__((ext_vector_type(4))) unsigned int u32x4;

#define GLL16(gsrc, ldst)                                                     \
    __builtin_amdgcn_global_load_lds(                                         \
        (const __attribute__((address_space(1))) void*)(gsrc),                \
        (__attribute__((address_space(3))) void*)(ldst), 16, 0, 0)

static __device__ __forceinline__ u16 f2bf(float f) {
    unsigned u = __builtin_bit_cast(unsigned, f);
    unsigned r = u + 0x7FFFu + ((u >> 16) & 1u);  // round-to-nearest-even
    return (u16)(r >> 16);
}

// ---------------------------------------------------------------------------
// Kernel 1: Wo (E,E) fp32 row-major -> WoT (n,k) bf16 (transposed), tiled.
// ---------------------------------------------------------------------------
__global__ __launch_bounds__(256) void prep_wot_k(const float* __restrict__ Wo,
                                                  u16* __restrict__ WoT) {
    __shared__ float tl[64][68];
    const int k0 = blockIdx.x * 64, n0 = blockIdx.y * 64;
    const int rr = threadIdx.x >> 2;
    const int c4 = (threadIdx.x & 3) * 16;
#pragma unroll
    for (int j = 0; j < 4; ++j)
        *(f32x4*)(&tl[rr][c4 + j * 4]) =
            *(const f32x4*)(Wo + (size_t)(k0 + rr) * 1024 + n0 + c4 + j * 4);
    __syncthreads();
    unsigned pk[8];
#pragma unroll
    for (int j = 0; j < 8; ++j)
        pk[j] = (unsigned)f2bf(tl[c4 + 2 * j][rr]) |
                ((unsigned)f2bf(tl[c4 + 2 * j + 1][rr]) << 16);
    u16* dst = WoT + (size_t)(n0 + rr) * 1024 + k0 + c4;
    *(u32x4*)(dst)     = u32x4{pk[0], pk[1], pk[2], pk[3]};
    *(u32x4*)(dst + 8) = u32x4{pk[4], pk[5], pk[6], pk[7]};
}

// ---------------------------------------------------------------------------
// Kernel 2: per-head Dense(D) projections, fp32 compute, bf16 output.
// out[((n*H+h)*S+s)*64+d] = sum_k X[n,s,h*64+k] * W[k][d]
// grid: (128 token-tiles of 64, 16 heads), 256 threads.
// ---------------------------------------------------------------------------
__global__ __launch_bounds__(256) void proj3(
    const float* __restrict__ xv, const float* __restrict__ xk,
    const float* __restrict__ xq, const float* __restrict__ Wv,
    const float* __restrict__ Wk, const float* __restrict__ Wq,
    u16* __restrict__ vout, u16* __restrict__ kout, u16* __restrict__ qout) {
    __shared__ float Xs[64][68];   // +4 pad: breaks 64-float stride conflicts
    __shared__ float Ws[64][64];   // reads are mostly broadcast
    const int tid = threadIdx.x;
    const int rr = tid >> 2;          // token row in tile / W row
    const int c4 = (tid & 3) * 16;    // output-col group
    const int t0 = blockIdx.x * 64;   // global token base (never crosses n)
    const int h = blockIdx.y;
    const int n = t0 >> 11;
    const int srow = t0 & 2047;

    const float* X[3] = {xv, xk, xq};
    const float* W[3] = {Wv, Wk, Wq};
    u16* O[3] = {vout, kout, qout};

#pragma unroll
    for (int tz = 0; tz < 3; ++tz) {
#pragma unroll
        for (int j = 0; j < 4; ++j) {
            *(f32x4*)(&Ws[rr][c4 + j * 4]) =
                *(const f32x4*)(W[tz] + rr * 64 + c4 + j * 4);
            *(f32x4*)(&Xs[rr][c4 + j * 4]) = *(const f32x4*)(
                X[tz] + (size_t)(t0 + rr) * 1024 + h * 64 + c4 + j * 4);
        }
        __syncthreads();
        float acc[16];
#pragma unroll
        for (int j = 0; j < 16; ++j) acc[j] = 0.f;
#pragma unroll 4
        for (int k = 0; k < 64; ++k) {
            float xval = Xs[rr][k];
#pragma unroll
            for (int j = 0; j < 16; ++j) acc[j] += xval * Ws[k][c4 + j];
        }
        unsigned pk[8];
#pragma unroll
        for (int j = 0; j < 8; ++j)
            pk[j] = (unsigned)f2bf(acc[2 * j]) |
                    ((unsigned)f2bf(acc[2 * j + 1]) << 16);
        u16* dst =
            O[tz] + ((size_t)(n * 16 + h) * 2048 + srow + rr) * 64 + c4;
        *(u32x4*)(dst)     = u32x4{pk[0], pk[1], pk[2], pk[3]};
        *(u32x4*)(dst + 8) = u32x4{pk[4], pk[5], pk[6], pk[7]};
        __syncthreads();
    }
}

// ---------------------------------------------------------------------------
// Kernel 3: flash attention. One block = 128 q-rows of one (n,h).
// 4 waves x 32 q-rows. KVBLK=64. 16x16x32 bf16 MFMA.
//  - Q fragments in registers (loaded once).
//  - K tile: global_load_lds, XOR chunk swizzle via pre-swizzled global src.
//  - V tile: reg-staged (issue loads early, ds_write after compute),
//            stored transposed [d][k], swizzle slot = (d&7)^(d>>3) so the
//            per-instruction ds_write_b16 spreads over all 32 banks.
//  - P: per-wave swizzled LDS round-trip (C-layout -> A-fragment layout).
//  - online softmax; per-lane partial row-sums, one cross-lane reduce at end.
// ---------------------------------------------------------------------------
__global__ __launch_bounds__(256, 2) void attn_fused(
    const u16* __restrict__ qb, const u16* __restrict__ kb,
    const u16* __restrict__ vb, const float* __restrict__ mask,
    u16* __restrict__ ob) {
    __shared__ char Kl[2][8192];  // [k][chunk c ^ (k&7)] 16B chunks
    __shared__ char Vt[2][8192];  // [d][ (k*2) ^ (((d&7)^(d>>3))<<4) ]
    __shared__ char Pl[4][4096];  // per-wave, [qh][kh*2 ^ ((qh&7)<<4)]

    const int tid = threadIdx.x;
    const int w = tid >> 6;
    const int l = tid & 63;
    const int g = l >> 4;
    const int lr = l & 15;
    const int nh = blockIdx.y;
    const int n = nh >> 4, h = nh & 15;
    const int q0 = blockIdx.x * 128 + w * 32;

    const u16* Qg = qb + (size_t)nh * (2048 * 64);
    const u16* Kg = kb + (size_t)nh * (2048 * 64);
    const u16* Vg = vb + (size_t)nh * (2048 * 64);

    // Q A-fragments: lane holds Q[q0+mt*16+lr][ks*32+g*8 .. +7]
    s16x8 aq[2][2];
#pragma unroll
    for (int mt = 0; mt < 2; ++mt)
#pragma unroll
        for (int ks = 0; ks < 2; ++ks)
            aq[mt][ks] = *(const s16x8*)(Qg +
                (size_t)(q0 + mt * 16 + lr) * 64 + ks * 32 + g * 8);

    f32x4 oacc[2][4];
    float mrow[2][4], lpart[2][4];
#pragma unroll
    for (int mt = 0; mt < 2; ++mt) {
#pragma unroll
        for (int r = 0; r < 4; ++r) { mrow[mt][r] = -1e30f; lpart[mt][r] = 0.f; }
#pragma unroll
        for (int nd = 0; nd < 4; ++nd) oacc[mt][nd] = f32x4{0.f, 0.f, 0.f, 0.f};
    }

    u32x4 vreg[2];
    // ---- prologue: stage tile 0 ----
#pragma unroll
    for (int i = 0; i < 2; ++i) {
        int j = w * 2 + i;
        int kk = j * 8 + (l >> 3);
        int c = (l & 7) ^ (kk & 7);
        GLL16(Kg + (size_t)kk * 64 + c * 8, &Kl[0][j * 1024]);
    }
#pragma unroll
    for (int it = 0; it < 2; ++it) {
        int kk = it * 32 + (tid >> 3);
        int dc = tid & 7;
        vreg[it] = *(const u32x4*)(Vg + (size_t)kk * 64 + dc * 8);
    }
#pragma unroll
    for (int it = 0; it < 2; ++it) {
        int kk = it * 32 + (tid >> 3);
        int dc = tid & 7;
        u16x8 vv = __builtin_bit_cast(u16x8, vreg[it]);
#pragma unroll
        for (int jj = 0; jj < 8; ++jj) {
            int d = dc * 8 + jj;  // d&7 == jj, d>>3 == dc
            *(u16*)(&Vt[0][d * 128 + ((kk * 2) ^ ((jj ^ dc) << 4))]) = vv[jj];
        }
    }
    __syncthreads();

    for (int t = 0; t < 32; ++t) {
        const int buf = t & 1;
        const int kv0 = t * 64;
        if (t < 31) {  // prefetch issue for tile t+1
#pragma unroll
            for (int i = 0; i < 2; ++i) {
                int j = w * 2 + i;
                int kk = j * 8 + (l >> 3);
                int c = (l & 7) ^ (kk & 7);
                GLL16(Kg + (size_t)(kv0 + 64 + kk) * 64 + c * 8,
                      &Kl[buf ^ 1][j * 1024]);
            }
#pragma unroll
            for (int it = 0; it < 2; ++it) {
                int kk = it * 32 + (tid >> 3);
                int dc = tid & 7;
                vreg[it] = *(const u32x4*)(Vg + (size_t)(kv0 + 64 + kk) * 64 + dc * 8);
            }
        }

        // ---- QK^T: S[q][k] ----
        f32x4 sacc[2][4];
#pragma unroll
        for (int mt = 0; mt < 2; ++mt)
#pragma unroll
            for (int nt = 0; nt < 4; ++nt) sacc[mt][nt] = f32x4{0.f, 0.f, 0.f, 0.f};
#pragma unroll
        for (int ks = 0; ks < 2; ++ks) {
            s16x8 bk[4];
#pragma unroll
            for (int nt = 0; nt < 4; ++nt) {
                int krow = nt * 16 + lr;
                int c = (ks * 4 + g) ^ (krow & 7);
                bk[nt] = *(const s16x8*)(&Kl[buf][krow * 128 + c * 16]);
            }
#pragma unroll
            for (int mt = 0; mt < 2; ++mt)
#pragma unroll
                for (int nt = 0; nt < 4; ++nt)
                    sacc[mt][nt] = __builtin_amdgcn_mfma_f32_16x16x32_bf16(
                        aq[mt][ks], bk[nt], sacc[mt][nt], 0, 0, 0);
        }

        float mv[4];
#pragma unroll
        for (int nt = 0; nt < 4; ++nt)
            mv[nt] = mask[(size_t)n * 2048 + kv0 + nt * 16 + lr];

        // ---- online softmax (per mt: 16 q-rows, lane's rows = g*4+r) ----
#pragma unroll
        for (int mt = 0; mt < 2; ++mt) {
            float lg[4][4];
#pragma unroll
            for (int nt = 0; nt < 4; ++nt)
#pragma unroll
                for (int r = 0; r < 4; ++r)
                    lg[r][nt] = (mv[nt] != 0.f) ? sacc[mt][nt][r] * 0.03125f
                                                : (-1e20f * 0.03125f);
#pragma unroll
            for (int r = 0; r < 4; ++r) {
                float rm = fmaxf(fmaxf(lg[r][0], lg[r][1]),
                                 fmaxf(lg[r][2], lg[r][3]));
#pragma unroll
                for (int off = 1; off < 16; off <<= 1)
                    rm = fmaxf(rm, __shfl_xor(rm, off, 64));
                float mold = mrow[mt][r];
                float mnew = fmaxf(mold, rm);
                mrow[mt][r] = mnew;
                float corr = __expf(mold - mnew);
                float ps = 0.f;
#pragma unroll
                for (int nt = 0; nt < 4; ++nt) {
                    float p = __expf(lg[r][nt] - mnew);
                    lg[r][nt] = p;
                    ps += p;
                }
                lpart[mt][r] = lpart[mt][r] * corr + ps;  // per-lane partial
#pragma unroll
                for (int nd = 0; nd < 4; ++nd) oacc[mt][nd][r] *= corr;
            }
            // write P tile (bf16, swizzled), per-wave private
#pragma unroll
            for (int r = 0; r < 4; ++r) {
                int qh = mt * 16 + g * 4 + r;
#pragma unroll
                for (int nt = 0; nt < 4; ++nt) {
                    int kh = nt * 16 + lr;
                    *(u16*)(&Pl[w][qh * 128 + ((kh * 2) ^ ((qh & 7) << 4))]) =
                        f2bf(lg[r][nt]);
                }
            }
        }

        // ---- PV: O[q][d] += P @ V ----
#pragma unroll
        for (int ks2 = 0; ks2 < 2; ++ks2) {
            s16x8 ap[2], bv[4];
#pragma unroll
            for (int mt = 0; mt < 2; ++mt) {
                int qh = mt * 16 + lr;
                ap[mt] = *(const s16x8*)(&Pl[w][qh * 128 +
                             ((ks2 * 64 + g * 16) ^ ((qh & 7) << 4))]);
            }
#pragma unroll
            for (int nd = 0; nd < 4; ++nd) {
                int d = nd * 16 + lr;
                int sw = ((d & 7) ^ ((d >> 3) & 7)) << 4;
                bv[nd] = *(const s16x8*)(&Vt[buf][d * 128 +
                             ((ks2 * 64 + g * 16) ^ sw)]);
            }
#pragma unroll
            for (int mt = 0; mt < 2; ++mt)
#pragma unroll
                for (int nd = 0; nd < 4; ++nd)
                    oacc[mt][nd] = __builtin_amdgcn_mfma_f32_16x16x32_bf16(
                        ap[mt], bv[nd], oacc[mt][nd], 0, 0, 0);
        }

        if (t < 31) {  // late write of prefetched V (hides HBM latency)
#pragma unroll
            for (int it = 0; it < 2; ++it) {
                int kk = it * 32 + (tid >> 3);
                int dc = tid & 7;
                u16x8 vv = __builtin_bit_cast(u16x8, vreg[it]);
#pragma unroll
                for (int jj = 0; jj < 8; ++jj) {
                    int d = dc * 8 + jj;
                    *(u16*)(&Vt[buf ^ 1][d * 128 + ((kk * 2) ^ ((jj ^ dc) << 4))]) = vv[jj];
                }
            }
        }
        __syncthreads();
    }

    // ---- epilogue: reduce row sums across 16 lanes, normalize, store ----
#pragma unroll
    for (int mt = 0; mt < 2; ++mt)
#pragma unroll
        for (int r = 0; r < 4; ++r) {
            float s = lpart[mt][r];
#pragma unroll
            for (int off = 1; off < 16; off <<= 1) s += __shfl_xor(s, off, 64);
            float inv = 1.0f / s;
            int q = q0 + mt * 16 + g * 4 + r;
            size_t obase = ((size_t)n * 2048 + q) * 1024 + h * 64;
#pragma unroll
            for (int nd = 0; nd < 4; ++nd)
                ob[obase + nd * 16 + lr] = f2bf(oacc[mt][nd][r] * inv);
        }
}

// ---------------------------------------------------------------------------
// Kernel 4: C = A(8192x1024,bf16) @ Wo + bo, via WoT(n,k) bf16. fp32 out.
// 128x128 tile, BK=32 (64-byte LDS rows: naturally conflict-free), dbuf.
// ---------------------------------------------------------------------------
__global__ __launch_bounds__(256, 2) void ogemm(const u16* __restrict__ A,
                                                const u16* __restrict__ B,
                                                const float* __restrict__ bias,
                                                float* __restrict__ C) {
    __shared__ char Al[2][8192];
    __shared__ char Bl[2][8192];
    const int tid = threadIdx.x;
    const int w = tid >> 6, l = tid & 63, g = l >> 4, lr = l & 15;
    const int m0 = blockIdx.x * 128, n0 = blockIdx.y * 128;
    const int wr = w >> 1, wc = w & 1;

    f32x4 acc[4][4];
#pragma unroll
    for (int mt = 0; mt < 4; ++mt)
#pragma unroll
        for (int nt = 0; nt < 4; ++nt) acc[mt][nt] = f32x4{0.f, 0.f, 0.f, 0.f};

    auto stage = [&](int bufi, int kt) {
#pragma unroll
        for (int i = 0; i < 2; ++i) {
            int j = w * 2 + i;
            int rrow = j * 16 + (l >> 2);
            int c = l & 3;
            GLL16(A + (size_t)(m0 + rrow) * 1024 + kt * 32 + c * 8,
                  &Al[bufi][j * 1024]);
            GLL16(B + (size_t)(n0 + rrow) * 1024 + kt * 32 + c * 8,
                  &Bl[bufi][j * 1024]);
        }
    };
    stage(0, 0);
    __syncthreads();
    for (int kt = 0; kt < 32; ++kt) {
        const int buf = kt & 1;
        if (kt < 31) stage(buf ^ 1, kt + 1);
        s16x8 a[4], b[4];
#pragma unroll
        for (int mt = 0; mt < 4; ++mt)
            a[mt] = *(const s16x8*)(&Al[buf][(wr * 64 + mt * 16 + lr) * 64 + g * 16]);
#pragma unroll
        for (int nt = 0; nt < 4; ++nt)
            b[nt] = *(const s16x8*)(&Bl[buf][(wc * 64 + nt * 16 + lr) * 64 + g * 16]);
#pragma unroll
        for (int mt = 0; mt < 4; ++mt)
#pragma unroll
            for (int nt = 0; nt < 4; ++nt)
                acc[mt][nt] = __builtin_amdgcn_mfma_f32_16x16x32_bf16(
                    a[mt], b[nt], acc[mt][nt], 0, 0, 0);
        __syncthreads();
    }
#pragma unroll
    for (int nt = 0; nt < 4; ++nt) {
        int ncol = n0 + wc * 64 + nt * 16 + lr;
        float bv = bias[ncol];
#pragma unroll
        for (int mt = 0; mt < 4; ++mt)
#pragma unroll
            for (int r = 0; r < 4; ++r) {
                int m = m0 + wr * 64 + mt * 16 + g * 4 + r;
                C[(size_t)m * 1024 + ncol] = acc[mt][nt][r] + bv;
            }
    }
}

// ---------------------------------------------------------------------------
extern "C" void kernel_launch(void* const* d_in, const int* in_sizes, int n_in,
                              void* d_out, int out_size, void* d_ws,
                              size_t ws_size, hipStream_t stream) {
    const float* values = (const float*)d_in[0];
    const float* keys   = (const float*)d_in[1];
    const float* query  = (const float*)d_in[2];
    const float* mask   = (const float*)d_in[3];
    const float* Wv     = (const float*)d_in[4];
    const float* Wk     = (const float*)d_in[5];
    const float* Wq     = (const float*)d_in[6];
    const float* Wo     = (const float*)d_in[7];
    const float* bo     = (const float*)d_in[8];
    float* out = (float*)d_out;

    char* ws = (char*)d_ws;
    const size_t SZ = 16777216;  // 8.4M bf16 elements
    u16* qbf = (u16*)(ws + 0 * SZ);
    u16* kbf = (u16*)(ws + 1 * SZ);
    u16* vbf = (u16*)(ws + 2 * SZ);
    u16* obf = (u16*)(ws + 3 * SZ);
    u16* wot = (u16*)(ws + 4 * SZ);

    prep_wot_k<<<dim3(16, 16), dim3(256), 0, stream>>>(Wo, wot);
    proj3<<<dim3(128, 16), dim3(256), 0, stream>>>(values, keys, query, Wv, Wk,
                                                   Wq, vbf, kbf, qbf);
    attn_fused<<<dim3(16, 64), dim3(256), 0, stream>>>(qbf, kbf, vbf, mask, obf);
    ogemm<<<dim3(64, 8), dim3(256), 0, stream>>>(obf, wot, bo, out);
}

// Round 4
// 357.173 us; speedup vs baseline: 1.1487x; 1.1487x over previous
//
#include <hip/hip_runtime.h>

// ---------------------------------------------------------------------------
// SelfAttention fused pipeline for MI355X (gfx950)
// N=4, S=2048, E=1024, H=16, D=64.
// Pipeline: [prep Wo^T + Wqkv^T bf16] -> [MFMA QKV proj, no LDS] ->
//           [flash attention bf16 MFMA] -> [out GEMM bf16 MFMA + bias, fp32]
// R2: attn defer-max (T13, log2 domain), ones-MFMA rowsum, exp2 softmax,
//     mask->bias, XCD swizzle (T1).
// R3: proj3 -> proj3_mfma (direct-global MFMA, no LDS; saves ~70 µs of
//     LDS-BW-bound VALU loop), + prep_wt3 for bf16 W^T.
// ---------------------------------------------------------------------------

typedef unsigned short u16;
typedef __attribute__((ext_vector_type(8))) short s16x8;
typedef __attribute__((ext_vector_type(8))) unsigned short u16x8;
typedef __attribute__((ext_vector_type(4))) float f32x4;
typedef __attribute__((ext_vector_type(4))) unsigned int u32x4;

#define GLL16(gsrc, ldst)                                                     \
    __builtin_amdgcn_global_load_lds(                                         \
        (const __attribute__((address_space(1))) void*)(gsrc),                \
        (__attribute__((address_space(3))) void*)(ldst), 16, 0, 0)

#if __has_builtin(__builtin_amdgcn_exp2f)
#define EXP2(x) __builtin_amdgcn_exp2f(x)
#else
#define EXP2(x) exp2f(x)
#endif

static __device__ __forceinline__ u16 f2bf(float f) {
    unsigned u = __builtin_bit_cast(unsigned, f);
    unsigned r = u + 0x7FFFu + ((u >> 16) & 1u);  // round-to-nearest-even
    return (u16)(r >> 16);
}
// cheap round-half-up (p >= 0, no NaN): 2 VALU ops
static __device__ __forceinline__ u16 f2bf_fast(float f) {
    return (u16)((__builtin_bit_cast(unsigned, f) + 0x8000u) >> 16);
}

// ---------------------------------------------------------------------------
// Kernel 1a: Wo (E,E) fp32 row-major -> WoT (n,k) bf16 (transposed), tiled.
// ---------------------------------------------------------------------------
__global__ __launch_bounds__(256) void prep_wot_k(const float* __restrict__ Wo,
                                                  u16* __restrict__ WoT) {
    __shared__ float tl[64][68];
    const int k0 = blockIdx.x * 64, n0 = blockIdx.y * 64;
    const int rr = threadIdx.x >> 2;
    const int c4 = (threadIdx.x & 3) * 16;
#pragma unroll
    for (int j = 0; j < 4; ++j)
        *(f32x4*)(&tl[rr][c4 + j * 4]) =
            *(const f32x4*)(Wo + (size_t)(k0 + rr) * 1024 + n0 + c4 + j * 4);
    __syncthreads();
    unsigned pk[8];
#pragma unroll
    for (int j = 0; j < 8; ++j)
        pk[j] = (unsigned)f2bf(tl[c4 + 2 * j][rr]) |
                ((unsigned)f2bf(tl[c4 + 2 * j + 1][rr]) << 16);
    u16* dst = WoT + (size_t)(n0 + rr) * 1024 + k0 + c4;
    *(u32x4*)(dst)     = u32x4{pk[0], pk[1], pk[2], pk[3]};
    *(u32x4*)(dst + 8) = u32x4{pk[4], pk[5], pk[6], pk[7]};
}

// ---------------------------------------------------------------------------
// Kernel 1b: Wv/Wk/Wq (64,64) fp32 -> W^T bf16 (3 blocks, one each).
// ---------------------------------------------------------------------------
__global__ __launch_bounds__(256) void prep_wt3(const float* __restrict__ Wv,
                                                const float* __restrict__ Wk,
                                                const float* __restrict__ Wq,
                                                u16* __restrict__ wt) {
    __shared__ float tl[64][65];
    const float* W = blockIdx.x == 0 ? Wv : (blockIdx.x == 1 ? Wk : Wq);
    u16* dst = wt + blockIdx.x * 4096;
    const int r = threadIdx.x >> 2;
    const int c = (threadIdx.x & 3) * 16;
#pragma unroll
    for (int j = 0; j < 4; ++j)
        *(f32x4*)(&tl[r][c + j * 4]) = *(const f32x4*)(W + r * 64 + c + j * 4);
    __syncthreads();
    unsigned pk[8];
#pragma unroll
    for (int j = 0; j < 8; ++j)
        pk[j] = (unsigned)f2bf(tl[c + 2 * j][r]) |
                ((unsigned)f2bf(tl[c + 2 * j + 1][r]) << 16);
    u16* d = dst + r * 64 + c;
    *(u32x4*)(d)     = u32x4{pk[0], pk[1], pk[2], pk[3]};
    *(u32x4*)(d + 8) = u32x4{pk[4], pk[5], pk[6], pk[7]};
}

// ---------------------------------------------------------------------------
// Kernel 2: per-head Dense(D) projections via MFMA, no LDS, no barriers.
// C = X(128x64 per block-head) @ W; A-frags direct from global fp32 (each
// element read once, 128B segments), B-frags from L1-hot bf16 W^T.
// grid (64 token-tiles of 128, 16 heads), 256 threads (4 waves x 32 rows).
// ---------------------------------------------------------------------------
__global__ __launch_bounds__(256) void proj3_mfma(
    const float* __restrict__ xv, const float* __restrict__ xk,
    const float* __restrict__ xq, const u16* __restrict__ wt3,
    u16* __restrict__ vout, u16* __restrict__ kout, u16* __restrict__ qout) {
    const int tid = threadIdx.x;
    const int w = tid >> 6, l = tid & 63, g = l >> 4, lr = l & 15;
    const int t0 = blockIdx.x * 128;
    const int h = blockIdx.y;
    const int n = t0 >> 11;
    const int srow = t0 & 2047;
    const int r0 = w * 32;  // wave's token base within tile

    const float* X[3] = {xv, xk, xq};
    u16* O[3] = {vout, kout, qout};

#pragma unroll
    for (int tz = 0; tz < 3; ++tz) {
        const u16* WT = wt3 + tz * 4096;
        // B-frags [ks][nd]: WT[d=nd*16+lr][k=ks*32+g*8 ..+7], L1-hot
        s16x8 bw[2][4];
#pragma unroll
        for (int ks = 0; ks < 2; ++ks)
#pragma unroll
            for (int nd = 0; nd < 4; ++nd)
                bw[ks][nd] = *(const s16x8*)(WT + (nd * 16 + lr) * 64 +
                                             ks * 32 + g * 8);
        // A-frags [mt][ks]: X[t0+r0+mt*16+lr][h*64 + ks*32 + g*8 ..+7]
        s16x8 ax[2][2];
#pragma unroll
        for (int mt = 0; mt < 2; ++mt)
#pragma unroll
            for (int ks = 0; ks < 2; ++ks) {
                const float* src = X[tz] +
                    (size_t)(t0 + r0 + mt * 16 + lr) * 1024 + h * 64 +
                    ks * 32 + g * 8;
                f32x4 x0 = *(const f32x4*)(src);
                f32x4 x1 = *(const f32x4*)(src + 4);
                union { s16x8 v; u16 e[8]; } u;
#pragma unroll
                for (int j = 0; j < 4; ++j) {
                    u.e[j]     = f2bf(x0[j]);
                    u.e[4 + j] = f2bf(x1[j]);
                }
                ax[mt][ks] = u.v;
            }
        f32x4 acc[2][4];
#pragma unroll
        for (int mt = 0; mt < 2; ++mt)
#pragma unroll
            for (int nd = 0; nd < 4; ++nd) acc[mt][nd] = f32x4{0.f, 0.f, 0.f, 0.f};
#pragma unroll
        for (int ks = 0; ks < 2; ++ks)
#pragma unroll
            for (int mt = 0; mt < 2; ++mt)
#pragma unroll
                for (int nd = 0; nd < 4; ++nd)
                    acc[mt][nd] = __builtin_amdgcn_mfma_f32_16x16x32_bf16(
                        ax[mt][ks], bw[ks][nd], acc[mt][nd], 0, 0, 0);
        // store: C col = lr (d), row = 4g+r
        u16* Ob = O[tz] + ((size_t)(n * 16 + h) * 2048 + srow + r0) * 64;
#pragma unroll
        for (int mt = 0; mt < 2; ++mt)
#pragma unroll
            for (int nd = 0; nd < 4; ++nd)
#pragma unroll
                for (int r = 0; r < 4; ++r)
                    Ob[(size_t)(mt * 16 + g * 4 + r) * 64 + nd * 16 + lr] =
                        f2bf(acc[mt][nd][r]);
    }
}

// ---------------------------------------------------------------------------
// Kernel 3: flash attention. 1D grid (1024 wg), XCD-swizzled.
// One block = 128 q-rows of one (n,h); 4 waves x 32 q-rows; KVBLK=64.
// Softmax in log2 domain with defer-max; row-sums via ones-MFMA.
// ---------------------------------------------------------------------------
__global__ __launch_bounds__(256, 2) void attn_fused(
    const u16* __restrict__ qb, const u16* __restrict__ kb,
    const u16* __restrict__ vb, const float* __restrict__ mask,
    u16* __restrict__ ob) {
    __shared__ char Kl[2][8192];  // [k][chunk c ^ (k&7)] 16B chunks
    __shared__ char Vt[2][8192];  // [d][ (k*2) ^ (((d&7)^(d>>3))<<4) ]
    __shared__ char Pl[4][4096];  // per-wave, [qh][kh*2 ^ ((qh&7)<<4)]

    const int tid = threadIdx.x;
    const int w = tid >> 6;
    const int l = tid & 63;
    const int g = l >> 4;
    const int lr = l & 15;
    // T1: bijective XCD swizzle (1024 % 8 == 0). Same-(n,h) q-blocks land on
    // one XCD so K/V stay L2-resident.
    const int bid = blockIdx.x;
    const int swz = (bid & 7) * 128 + (bid >> 3);
    const int nh = swz >> 4;
    const int qt = swz & 15;
    const int n = nh >> 4, h = nh & 15;
    const int q0 = qt * 128 + w * 32;

    const u16* Qg = qb + (size_t)nh * (2048 * 64);
    const u16* Kg = kb + (size_t)nh * (2048 * 64);
    const u16* Vg = vb + (size_t)nh * (2048 * 64);

    const float CSC = 0.04508422f;  // (1/sqrt(1024)) * log2(e)
    const float THR = 8.0f;         // defer-max threshold (log2 domain)
    const short one_bf = (short)0x3F80;
    const s16x8 vones = {one_bf, one_bf, one_bf, one_bf,
                         one_bf, one_bf, one_bf, one_bf};

    // Q A-fragments: lane holds Q[q0+mt*16+lr][ks*32+g*8 .. +7]
    s16x8 aq[2][2];
#pragma unroll
    for (int mt = 0; mt < 2; ++mt)
#pragma unroll
        for (int ks = 0; ks < 2; ++ks)
            aq[mt][ks] = *(const s16x8*)(Qg +
                (size_t)(q0 + mt * 16 + lr) * 64 + ks * 32 + g * 8);

    f32x4 oacc[2][4];
    f32x4 osum[2];
    float mrow[2][4];
    float wmin = -1e30f;
#pragma unroll
    for (int mt = 0; mt < 2; ++mt) {
        osum[mt] = f32x4{0.f, 0.f, 0.f, 0.f};
#pragma unroll
        for (int r = 0; r < 4; ++r) mrow[mt][r] = -1e30f;
#pragma unroll
        for (int nd = 0; nd < 4; ++nd) oacc[mt][nd] = f32x4{0.f, 0.f, 0.f, 0.f};
    }

    u32x4 vreg[2];
    // ---- prologue: stage tile 0 ----
#pragma unroll
    for (int i = 0; i < 2; ++i) {
        int j = w * 2 + i;
        int kk = j * 8 + (l >> 3);
        int c = (l & 7) ^ (kk & 7);
        GLL16(Kg + (size_t)kk * 64 + c * 8, &Kl[0][j * 1024]);
    }
#pragma unroll
    for (int it = 0; it < 2; ++it) {
        int kk = it * 32 + (tid >> 3);
        int dc = tid & 7;
        vreg[it] = *(const u32x4*)(Vg + (size_t)kk * 64 + dc * 8);
    }
#pragma unroll
    for (int it = 0; it < 2; ++it) {
        int kk = it * 32 + (tid >> 3);
        int dc = tid & 7;
        u16x8 vv = __builtin_bit_cast(u16x8, vreg[it]);
#pragma unroll
        for (int jj = 0; jj < 8; ++jj) {
            int d = dc * 8 + jj;  // d&7 == jj, d>>3 == dc
            *(u16*)(&Vt[0][d * 128 + ((kk * 2) ^ ((jj ^ dc) << 4))]) = vv[jj];
        }
    }
    __syncthreads();

    for (int t = 0; t < 32; ++t) {
        const int buf = t & 1;
        const int kv0 = t * 64;

        // mask loads first: L2 latency hides under prefetch-issue + QK^T
        float mv[4];
#pragma unroll
        for (int nt = 0; nt < 4; ++nt)
            mv[nt] = mask[(size_t)n * 2048 + kv0 + nt * 16 + lr];

        if (t < 31) {  // prefetch issue for tile t+1
#pragma unroll
            for (int i = 0; i < 2; ++i) {
                int j = w * 2 + i;
                int kk = j * 8 + (l >> 3);
                int c = (l & 7) ^ (kk & 7);
                GLL16(Kg + (size_t)(kv0 + 64 + kk) * 64 + c * 8,
                      &Kl[buf ^ 1][j * 1024]);
            }
#pragma unroll
            for (int it = 0; it < 2; ++it) {
                int kk = it * 32 + (tid >> 3);
                int dc = tid & 7;
                vreg[it] = *(const u32x4*)(Vg + (size_t)(kv0 + 64 + kk) * 64 + dc * 8);
            }
        }

        // ---- QK^T: S[q][k] ----
        f32x4 sacc[2][4];
#pragma unroll
        for (int mt = 0; mt < 2; ++mt)
#pragma unroll
            for (int nt = 0; nt < 4; ++nt) sacc[mt][nt] = f32x4{0.f, 0.f, 0.f, 0.f};
#pragma unroll
        for (int ks = 0; ks < 2; ++ks) {
            s16x8 bk[4];
#pragma unroll
            for (int nt = 0; nt < 4; ++nt) {
                int krow = nt * 16 + lr;
                int c = (ks * 4 + g) ^ (krow & 7);
                bk[nt] = *(const s16x8*)(&Kl[buf][krow * 128 + c * 16]);
            }
#pragma unroll
            for (int mt = 0; mt < 2; ++mt)
#pragma unroll
                for (int nt = 0; nt < 4; ++nt)
                    sacc[mt][nt] = __builtin_amdgcn_mfma_f32_16x16x32_bf16(
                        aq[mt][ks], bk[nt], sacc[mt][nt], 0, 0, 0);
        }

        // ---- softmax, log2 domain ----
        float mb[4];
#pragma unroll
        for (int nt = 0; nt < 4; ++nt)
            mb[nt] = (mv[nt] != 0.f) ? 0.f : -1e30f;

        float lg[2][4][4];
#pragma unroll
        for (int mt = 0; mt < 2; ++mt)
#pragma unroll
            for (int nt = 0; nt < 4; ++nt)
#pragma unroll
                for (int r = 0; r < 4; ++r)
                    lg[mt][r][nt] = fmaf(sacc[mt][nt][r], CSC, mb[nt]);

        // per-lane tile max (compiler fuses fmaxf chains to v_max3)
        float tmax = lg[0][0][0];
#pragma unroll
        for (int mt = 0; mt < 2; ++mt)
#pragma unroll
            for (int r = 0; r < 4; ++r)
#pragma unroll
                for (int nt = 0; nt < 4; ++nt)
                    tmax = fmaxf(tmax, lg[mt][r][nt]);

        if (!__all(tmax <= wmin + THR)) {
            // SLOW path (rare: tile 0 + genuine max growth): exact row max,
            // rescale O and rowsum accumulators.
#pragma unroll
            for (int mt = 0; mt < 2; ++mt)
#pragma unroll
                for (int r = 0; r < 4; ++r) {
                    float rm = fmaxf(fmaxf(lg[mt][r][0], lg[mt][r][1]),
                                     fmaxf(lg[mt][r][2], lg[mt][r][3]));
#pragma unroll
                    for (int off = 1; off < 16; off <<= 1)
                        rm = fmaxf(rm, __shfl_xor(rm, off, 64));
                    float mold = mrow[mt][r];
                    float mnew = fmaxf(mold, rm);
                    float corr = EXP2(mold - mnew);
                    mrow[mt][r] = mnew;
                    osum[mt][r] *= corr;
#pragma unroll
                    for (int nd = 0; nd < 4; ++nd) oacc[mt][nd][r] *= corr;
                }
            float lmin = mrow[0][0];
#pragma unroll
            for (int mt = 0; mt < 2; ++mt)
#pragma unroll
                for (int r = 0; r < 4; ++r) lmin = fminf(lmin, mrow[mt][r]);
            lmin = fminf(lmin, __shfl_xor(lmin, 16, 64));
            lmin = fminf(lmin, __shfl_xor(lmin, 32, 64));
            wmin = lmin;
        }

        // P = exp2(lg - m_row), bf16, write swizzled (per-wave LDS)
#pragma unroll
        for (int mt = 0; mt < 2; ++mt)
#pragma unroll
            for (int r = 0; r < 4; ++r) {
                int qh = mt * 16 + g * 4 + r;
                float m = mrow[mt][r];
#pragma unroll
                for (int nt = 0; nt < 4; ++nt) {
                    float p = EXP2(lg[mt][r][nt] - m);
                    int kh = nt * 16 + lr;
                    *(u16*)(&Pl[w][qh * 128 + ((kh * 2) ^ ((qh & 7) << 4))]) =
                        f2bf_fast(p);
                }
            }

        // ---- PV: O += P @ V ; rowsum += P @ ones ----
#pragma unroll
        for (int ks2 = 0; ks2 < 2; ++ks2) {
            s16x8 ap[2], bv[4];
#pragma unroll
            for (int mt = 0; mt < 2; ++mt) {
                int qh = mt * 16 + lr;
                ap[mt] = *(const s16x8*)(&Pl[w][qh * 128 +
                             ((ks2 * 64 + g * 16) ^ ((qh & 7) << 4))]);
            }
#pragma unroll
            for (int nd = 0; nd < 4; ++nd) {
                int d = nd * 16 + lr;
                int sw = ((d & 7) ^ ((d >> 3) & 7)) << 4;
                bv[nd] = *(const s16x8*)(&Vt[buf][d * 128 +
                             ((ks2 * 64 + g * 16) ^ sw)]);
            }
#pragma unroll
            for (int mt = 0; mt < 2; ++mt) {
                osum[mt] = __builtin_amdgcn_mfma_f32_16x16x32_bf16(
                    ap[mt], vones, osum[mt], 0, 0, 0);
#pragma unroll
                for (int nd = 0; nd < 4; ++nd)
                    oacc[mt][nd] = __builtin_amdgcn_mfma_f32_16x16x32_bf16(
                        ap[mt], bv[nd], oacc[mt][nd], 0, 0, 0);
            }
        }

        if (t < 31) {  // late write of prefetched V (hides HBM latency)
#pragma unroll
            for (int it = 0; it < 2; ++it) {
                int kk = it * 32 + (tid >> 3);
                int dc = tid & 7;
                u16x8 vv = __builtin_bit_cast(u16x8, vreg[it]);
#pragma unroll
                for (int jj = 0; jj < 8; ++jj) {
                    int d = dc * 8 + jj;
                    *(u16*)(&Vt[buf ^ 1][d * 128 + ((kk * 2) ^ ((jj ^ dc) << 4))]) = vv[jj];
                }
            }
        }
        __syncthreads();
    }

    // ---- epilogue: rowsum already per-lane (ones-MFMA); normalize, store ----
#pragma unroll
    for (int mt = 0; mt < 2; ++mt)
#pragma unroll
        for (int r = 0; r < 4; ++r) {
            float inv = 1.0f / osum[mt][r];
            int q = q0 + mt * 16 + g * 4 + r;
            size_t obase = ((size_t)n * 2048 + q) * 1024 + h * 64;
#pragma unroll
            for (int nd = 0; nd < 4; ++nd)
                ob[obase + nd * 16 + lr] = f2bf(oacc[mt][nd][r] * inv);
        }
}

// ---------------------------------------------------------------------------
// Kernel 4: C = A(8192x1024,bf16) @ Wo + bo, via WoT(n,k) bf16. fp32 out.
// ---------------------------------------------------------------------------
__global__ __launch_bounds__(256, 2) void ogemm(const u16* __restrict__ A,
                                                const u16* __restrict__ B,
                                                const float* __restrict__ bias,
                                                float* __restrict__ C) {
    __shared__ char Al[2][8192];
    __shared__ char Bl[2][8192];
    const int tid = threadIdx.x;
    const int w = tid >> 6, l = tid & 63, g = l >> 4, lr = l & 15;
    const int m0 = blockIdx.x * 128, n0 = blockIdx.y * 128;
    const int wr = w >> 1, wc = w & 1;

    f32x4 acc[4][4];
#pragma unroll
    for (int mt = 0; mt < 4; ++mt)
#pragma unroll
        for (int nt = 0; nt < 4; ++nt) acc[mt][nt] = f32x4{0.f, 0.f, 0.f, 0.f};

    auto stage = [&](int bufi, int kt) {
#pragma unroll
        for (int i = 0; i < 2; ++i) {
            int j = w * 2 + i;
            int rrow = j * 16 + (l >> 2);
            int c = l & 3;
            GLL16(A + (size_t)(m0 + rrow) * 1024 + kt * 32 + c * 8,
                  &Al[bufi][j * 1024]);
            GLL16(B + (size_t)(n0 + rrow) * 1024 + kt * 32 + c * 8,
                  &Bl[bufi][j * 1024]);
        }
    };
    stage(0, 0);
    __syncthreads();
    for (int kt = 0; kt < 32; ++kt) {
        const int buf = kt & 1;
        if (kt < 31) stage(buf ^ 1, kt + 1);
        s16x8 a[4], b[4];
#pragma unroll
        for (int mt = 0; mt < 4; ++mt)
            a[mt] = *(const s16x8*)(&Al[buf][(wr * 64 + mt * 16 + lr) * 64 + g * 16]);
#pragma unroll
        for (int nt = 0; nt < 4; ++nt)
            b[nt] = *(const s16x8*)(&Bl[buf][(wc * 64 + nt * 16 + lr) * 64 + g * 16]);
#pragma unroll
        for (int mt = 0; mt < 4; ++mt)
#pragma unroll
            for (int nt = 0; nt < 4; ++nt)
                acc[mt][nt] = __builtin_amdgcn_mfma_f32_16x16x32_bf16(
                    a[mt], b[nt], acc[mt][nt], 0, 0, 0);
        __syncthreads();
    }
#pragma unroll
    for (int nt = 0; nt < 4; ++nt) {
        int ncol = n0 + wc * 64 + nt * 16 + lr;
        float bv = bias[ncol];
#pragma unroll
        for (int mt = 0; mt < 4; ++mt)
#pragma unroll
            for (int r = 0; r < 4; ++r) {
                int m = m0 + wr * 64 + mt * 16 + g * 4 + r;
                C[(size_t)m * 1024 + ncol] = acc[mt][nt][r] + bv;
            }
    }
}

// ---------------------------------------------------------------------------
extern "C" void kernel_launch(void* const* d_in, const int* in_sizes, int n_in,
                              void* d_out, int out_size, void* d_ws,
                              size_t ws_size, hipStream_t stream) {
    const float* values = (const float*)d_in[0];
    const float* keys   = (const float*)d_in[1];
    const float* query  = (const float*)d_in[2];
    const float* mask   = (const float*)d_in[3];
    const float* Wv     = (const float*)d_in[4];
    const float* Wk     = (const float*)d_in[5];
    const float* Wq     = (const float*)d_in[6];
    const float* Wo     = (const float*)d_in[7];
    const float* bo     = (const float*)d_in[8];
    float* out = (float*)d_out;

    char* ws = (char*)d_ws;
    const size_t SZ = 16777216;  // 8.4M bf16 elements
    u16* qbf = (u16*)(ws + 0 * SZ);
    u16* kbf = (u16*)(ws + 1 * SZ);
    u16* vbf = (u16*)(ws + 2 * SZ);
    u16* obf = (u16*)(ws + 3 * SZ);
    u16* wot = (u16*)(ws + 4 * SZ);
    u16* wt3 = (u16*)(ws + 4 * SZ + 2097152);  // 3 x 64x64 bf16 W^T

    prep_wot_k<<<dim3(16, 16), dim3(256), 0, stream>>>(Wo, wot);
    prep_wt3<<<dim3(3), dim3(256), 0, stream>>>(Wv, Wk, Wq, wt3);
    proj3_mfma<<<dim3(64, 16), dim3(256), 0, stream>>>(values, keys, query,
                                                       wt3, vbf, kbf, qbf);
    attn_fused<<<dim3(1024), dim3(256), 0, stream>>>(qbf, kbf, vbf, mask, obf);
    ogemm<<<dim3(64, 8), dim3(256), 0, stream>>>(obf, wot, bo, out);
}